// Round 12
// baseline (993.346 us; speedup 1.0000x reference)
//
#include <hip/hip_runtime.h>
#include <hip/hip_bf16.h>

#define NN 50000
#define NE 1600000
#define FIN 64
#define H 128
#define NL 5
#define NG 512
#define NC 10

typedef __attribute__((ext_vector_type(8))) short short8;
typedef __attribute__((ext_vector_type(4))) float f32x4;

// ws float-word offsets (~65 MB)
#define OFF_H     0            // 6.4M floats
#define OFF_H2A   6400000      // bf16 h ping (3.2M words)
#define OFF_H2B   9600000      // bf16 h pong (3.2M words)
#define OFF_CUR   12800000     // 50016 ints
#define OFF_CSR   12850016     // 1.6M packed words (ushort src | bf16 w << 16)
#define OFF_POOL  16050016     // 65536 unsigned
#define OFF_FWF   16115552     // 245760 shorts (5 x 128x384 bf16 frag)
#define OFF_FWHH  16238432     // 49152 shorts

__device__ __forceinline__ short rne_bf16(float f){
    unsigned u = __float_as_uint(f);
    unsigned r = (u + 0x7FFFu + ((u >> 16) & 1u)) >> 16;
    return (short)r;
}
__device__ __forceinline__ float bf_lo(unsigned v){ return __uint_as_float(v << 16); }
__device__ __forceinline__ float bf_hi(unsigned v){ return __uint_as_float(v & 0xFFFF0000u); }

// ---------- CSR build ----------

__global__ void k_hist(const int* __restrict__ ei, int* __restrict__ cnt){
    int e = blockIdx.x*256 + threadIdx.x;
    if (e < NE) atomicAdd(&cnt[ei[NE + e]], 1);
}

__global__ void k_scan(int* __restrict__ cur){
    __shared__ int s[1024];
    int t = threadIdx.x;
    const int CH = 49;
    int base = t*CH;
    int m = NN - base; if (m > CH) m = CH; if (m < 0) m = 0;
    int sum = 0;
    for (int i = 0; i < m; ++i) sum += cur[base + i];
    s[t] = sum; __syncthreads();
    for (int off = 1; off < 1024; off <<= 1){
        int v = (t >= off) ? s[t - off] : 0; __syncthreads();
        s[t] += v; __syncthreads();
    }
    int run = s[t] - sum;
    for (int i = 0; i < m; ++i){
        int c = cur[base + i];
        cur[base + i] = run;
        run += c;
    }
}

// packed fill: ONE 4-byte store per edge (src in low 16, bf16 weight in high 16)
__global__ void k_fill(const int* __restrict__ ei, const float* __restrict__ ew,
                       int* __restrict__ cur, unsigned* __restrict__ csr){
    int e = blockIdx.x*256 + threadIdx.x;
    if (e >= NE) return;
    int src = ei[e], dst = ei[NE + e];
    int pos = atomicAdd(&cur[dst], 1);
    csr[pos] = (unsigned)src | (((unsigned)(ushort)rne_bf16(ew[e])) << 16);
}

// ---------- one-time prep ----------

__global__ void k_pad(const float* __restrict__ x, float* __restrict__ h,
                      ushort* __restrict__ h2a){
    int idx = blockIdx.x*256 + threadIdx.x;
    int n = idx >> 7, f = idx & 127;
    float v = (f < FIN) ? x[n*FIN + f] : 0.f;
    h[idx] = v;
    h2a[idx] = (ushort)rne_bf16(v);
}

// fragWf[l] = bf16-frag( W_l @ w_ih^T )   [K=128][N=384]
__global__ void k_fuse(const float* __restrict__ W, const float* __restrict__ wih,
                       short* __restrict__ fwf){
    int idx = blockIdx.x*256 + threadIdx.x;   // 0..245759
    int l = idx / 49152;
    int r = idx % 49152;
    int k = r / 384, n = r % 384;
    const float* wl = W + l*16384 + k*128;
    const float* wi = wih + n*128;
    float acc = 0.f;
    for (int c = 0; c < 128; ++c) acc += wl[c]*wi[c];
    int lane = ((k>>3)&3)*16 + (n&15);
    fwf[l*49152 + (((n>>4)*4 + (k>>5))*64 + lane)*8 + (k&7)] = rne_bf16(acc);
}

__global__ void k_cvt_whh(const float* __restrict__ whh, short* __restrict__ fwhh){
    int idx = blockIdx.x*256 + threadIdx.x;   // 0..49151
    int k = idx / 384, n = idx % 384;
    float v = whh[n*128 + k];
    int lane = ((k>>3)&3)*16 + (n&15);
    fwhh[(((n>>4)*4 + (k>>5))*64 + lane)*8 + (k&7)] = rne_bf16(v);
}

__global__ void k_init_pool(unsigned* __restrict__ p){
    p[blockIdx.x*256 + threadIdx.x] = 0x007FFFFFu;   // enc(-inf)
}

// ---------- fused layer: aggregate -> dual MFMA GEMM -> register GRU ----------
// Ping-pong h2; last=1 folds segment-max pooling into epilogue.
// Agg inner loop: per-64-batch pre-split (sv,wv), 2 shfl + 0 decode per edge.
__global__ __launch_bounds__(256)
void k_layer(float* __restrict__ h, const ushort* __restrict__ h2r,
             ushort* __restrict__ h2w,
             const int* __restrict__ cur, const unsigned* __restrict__ csr,
             const short* __restrict__ fwf, const short* __restrict__ fwhh,
             const float* __restrict__ b_ih, const float* __restrict__ b_hh,
             const int* __restrict__ batch, unsigned* __restrict__ pooled,
             int last){
    __shared__ ushort tl[16*136];             // row stride 136 ushorts (16B-aligned)
    int tid = threadIdx.x;
    int n0 = blockIdx.x * 16;
    int wave = tid >> 6, lane = tid & 63;
    int lane_lo = lane & 15, quad = lane >> 4;

    // ---- phase 1: pull-aggregate 4 nodes per wave into LDS (bf16) ----
    unsigned* tld = (unsigned*)tl;
    for (int sub = 0; sub < 4; ++sub){
        int node = n0 + wave*4 + sub;
        int start = (node == 0) ? 0 : cur[node - 1];
        int end   = cur[node];
        float ax = 0.f, ay = 0.f;
        const ushort* hp = h2r + lane*2;
        for (int base = start; base < end; base += 64){
            int i = base + lane;
            unsigned pkv = (i < end) ? csr[i] : 0;
            int   sv = (int)(pkv & 0xFFFFu);   // pre-split ONCE per 64-edge batch
            float wv = bf_hi(pkv);
            int m = end - base; if (m > 64) m = 64;
            int j = 0;
            for (; j + 8 <= m; j += 8){
                int   s0 = __shfl(sv, j+0), s1 = __shfl(sv, j+1);
                int   s2 = __shfl(sv, j+2), s3 = __shfl(sv, j+3);
                int   s4 = __shfl(sv, j+4), s5 = __shfl(sv, j+5);
                int   s6 = __shfl(sv, j+6), s7 = __shfl(sv, j+7);
                float w0 = __shfl(wv, j+0), w1 = __shfl(wv, j+1);
                float w2 = __shfl(wv, j+2), w3 = __shfl(wv, j+3);
                float w4 = __shfl(wv, j+4), w5 = __shfl(wv, j+5);
                float w6 = __shfl(wv, j+6), w7 = __shfl(wv, j+7);
                unsigned v0 = *(const unsigned*)(hp + s0*H);
                unsigned v1 = *(const unsigned*)(hp + s1*H);
                unsigned v2 = *(const unsigned*)(hp + s2*H);
                unsigned v3 = *(const unsigned*)(hp + s3*H);
                unsigned v4 = *(const unsigned*)(hp + s4*H);
                unsigned v5 = *(const unsigned*)(hp + s5*H);
                unsigned v6 = *(const unsigned*)(hp + s6*H);
                unsigned v7 = *(const unsigned*)(hp + s7*H);
                ax += w0*bf_lo(v0); ay += w0*bf_hi(v0);
                ax += w1*bf_lo(v1); ay += w1*bf_hi(v1);
                ax += w2*bf_lo(v2); ay += w2*bf_hi(v2);
                ax += w3*bf_lo(v3); ay += w3*bf_hi(v3);
                ax += w4*bf_lo(v4); ay += w4*bf_hi(v4);
                ax += w5*bf_lo(v5); ay += w5*bf_hi(v5);
                ax += w6*bf_lo(v6); ay += w6*bf_hi(v6);
                ax += w7*bf_lo(v7); ay += w7*bf_hi(v7);
            }
            for (; j < m; ++j){
                int   s = __shfl(sv, j);
                float w = __shfl(wv, j);
                unsigned v = *(const unsigned*)(hp + s*H);
                ax += w*bf_lo(v); ay += w*bf_hi(v);
            }
        }
        tld[(wave*4 + sub)*68 + lane] =
            ((unsigned)(ushort)rne_bf16(ax)) | (((unsigned)(ushort)rne_bf16(ay)) << 16);
    }
    __syncthreads();

    // ---- phase 2: dual GEMM; wave w owns cols w*32+{0..31} of each section ----
    f32x4 ai[6], ah[6];                       // [s*2 + t16]
    #pragma unroll
    for (int i = 0; i < 6; ++i){ ai[i] = (f32x4){0.f,0.f,0.f,0.f}; ah[i] = (f32x4){0.f,0.f,0.f,0.f}; }

    const ushort* arow_t = tl + lane_lo*136;
    const ushort* arow_h = h2r + (size_t)(n0 + lane_lo)*H;
    #pragma unroll
    for (int kt = 0; kt < 4; ++kt){
        short8 at  = *(const short8*)(arow_t + kt*32 + quad*8);
        short8 ahh = *(const short8*)(arow_h + kt*32 + quad*8);
        #pragma unroll
        for (int s = 0; s < 3; ++s){
            #pragma unroll
            for (int t16 = 0; t16 < 2; ++t16){
                int tile = (s*8 + wave*2 + t16)*4 + kt;
                short8 bi = *(const short8*)(fwf  + tile*512 + lane*8);
                short8 bh = *(const short8*)(fwhh + tile*512 + lane*8);
                ai[s*2+t16] = __builtin_amdgcn_mfma_f32_16x16x32_bf16(at,  bi, ai[s*2+t16], 0, 0, 0);
                ah[s*2+t16] = __builtin_amdgcn_mfma_f32_16x16x32_bf16(ahh, bh, ah[s*2+t16], 0, 0, 0);
            }
        }
    }

    // ---- phase 3: register-resident GRU update (+ fused pool on last) ----
    #pragma unroll
    for (int t16 = 0; t16 < 2; ++t16){
        int j = wave*32 + t16*16 + lane_lo;
        float bir = b_ih[j], biz = b_ih[128 + j], bin_ = b_ih[256 + j];
        float bhr = b_hh[j], bhz = b_hh[128 + j], bhn  = b_hh[256 + j];
        #pragma unroll
        for (int r = 0; r < 4; ++r){
            int row = n0 + quad*4 + r;
            float gir = ai[t16][r]     + bir, ghr = ah[t16][r]     + bhr;
            float giz = ai[2 + t16][r] + biz, ghz = ah[2 + t16][r] + bhz;
            float gin = ai[4 + t16][r] + bin_, ghn = ah[4 + t16][r] + bhn;
            float rr = 1.f/(1.f + __expf(-(gir + ghr)));
            float zz = 1.f/(1.f + __expf(-(giz + ghz)));
            float nn = tanhf(gin + rr*ghn);
            float ho = h[(size_t)row*H + j];
            float hv = (1.f - zz)*nn + zz*ho;
            if (!last){
                h[(size_t)row*H + j] = hv;
                h2w[(size_t)row*H + j] = (ushort)rne_bf16(hv);
            } else {
                int g = batch[row];
                unsigned u = __float_as_uint(hv);
                u = (u & 0x80000000u) ? ~u : (u | 0x80000000u);
                atomicMax(pooled + g*H + j, u);
            }
        }
    }
}

// ---------- tail ----------

__global__ void k_head(const unsigned* __restrict__ pooled,
                       const float* __restrict__ d1w, const float* __restrict__ d1b,
                       const float* __restrict__ d2w, const float* __restrict__ d2b,
                       float* __restrict__ out){
    __shared__ float sp[128];
    __shared__ float shid[512];
    int g = blockIdx.x, tid = threadIdx.x;
    if (tid < 128){
        unsigned u = pooled[g*H + tid];
        sp[tid] = __uint_as_float((u & 0x80000000u) ? (u ^ 0x80000000u) : ~u);
    }
    __syncthreads();
    for (int o = tid; o < 512; o += 256){
        float acc = d1b[o];
        for (int k = 0; k < H; ++k) acc += sp[k] * d1w[o*H + k];
        shid[o] = fmaxf(acc, 0.f);
    }
    __syncthreads();
    if (tid < NC){
        float acc = d2b[tid];
        for (int o = 0; o < 512; ++o) acc += shid[o] * d2w[tid*512 + o];
        out[g*NC + tid] = acc;
    }
}

extern "C" void kernel_launch(void* const* d_in, const int* in_sizes, int n_in,
                              void* d_out, int out_size, void* d_ws, size_t ws_size,
                              hipStream_t stream){
    const float* x     = (const float*)d_in[0];
    const int*   ei    = (const int*)d_in[1];
    const int*   batch = (const int*)d_in[2];
    const float* ew    = (const float*)d_in[3];
    const float* W     = (const float*)d_in[4];
    const float* wih   = (const float*)d_in[5];
    const float* whh   = (const float*)d_in[6];
    const float* bih   = (const float*)d_in[7];
    const float* bhh   = (const float*)d_in[8];
    const float* d1w   = (const float*)d_in[9];
    const float* d1b   = (const float*)d_in[10];
    const float* d2w   = (const float*)d_in[11];
    const float* d2b   = (const float*)d_in[12];
    float* out = (float*)d_out;

    float*  ws  = (float*)d_ws;
    float*  h   = ws + OFF_H;
    ushort* h2a = (ushort*)(ws + OFF_H2A);
    ushort* h2b = (ushort*)(ws + OFF_H2B);
    int*    cur = (int*)(ws + OFF_CUR);
    unsigned* csr = (unsigned*)(ws + OFF_CSR);
    unsigned* pooled = (unsigned*)(ws + OFF_POOL);
    short*  fwf  = (short*)(ws + OFF_FWF);
    short*  fwhh = (short*)(ws + OFF_FWHH);

    hipMemsetAsync(cur, 0, (size_t)NN*sizeof(int), stream);
    k_hist<<<6250, 256, 0, stream>>>(ei, cur);
    k_scan<<<1, 1024, 0, stream>>>(cur);
    k_fill<<<6250, 256, 0, stream>>>(ei, ew, cur, csr);

    k_fuse<<<960, 256, 0, stream>>>(W, wih, fwf);
    k_cvt_whh<<<192, 256, 0, stream>>>(whh, fwhh);
    k_pad<<<25000, 256, 0, stream>>>(x, h, h2a);
    k_init_pool<<<256, 256, 0, stream>>>(pooled);

    for (int l = 0; l < NL; ++l){
        ushort* h2r = (l & 1) ? h2b : h2a;
        ushort* h2w = (l & 1) ? h2a : h2b;
        k_layer<<<3125, 256, 0, stream>>>(h, h2r, h2w, cur, csr,
                                          fwf + (size_t)l*49152, fwhh, bih, bhh,
                                          batch, pooled, (l == NL-1) ? 1 : 0);
    }

    k_head<<<NG, 256, 0, stream>>>(pooled, d1w, d1b, d2w, d2b, out);
}

// Round 13
// 933.370 us; speedup vs baseline: 1.0643x; 1.0643x over previous
//
#include <hip/hip_runtime.h>
#include <hip/hip_bf16.h>

#define NN 50000
#define NE 1600000
#define FIN 64
#define H 128
#define NL 5
#define NG 512
#define NC 10

typedef __attribute__((ext_vector_type(8))) short short8;
typedef __attribute__((ext_vector_type(4))) float f32x4;

// ws word offsets (~33 MB total)
#define OFF_H2A   0            // bf16 h ping (3.2M words)
#define OFF_H2B   3200000      // bf16 h pong (3.2M words)
#define OFF_CUR   6400000      // 50016 ints
#define OFF_CSR   6450016      // 1.6M packed words (ushort src | bf16 w << 16)
#define OFF_POOL  8050016      // 65536 unsigned
#define OFF_FWF   8115552      // 245760 shorts (5 x 128x384 bf16 frag)
#define OFF_FWHH  8238432      // 49152 shorts

__device__ __forceinline__ short rne_bf16(float f){
    unsigned u = __float_as_uint(f);
    unsigned r = (u + 0x7FFFu + ((u >> 16) & 1u)) >> 16;
    return (short)r;
}
__device__ __forceinline__ float bf_lo(unsigned v){ return __uint_as_float(v << 16); }
__device__ __forceinline__ float bf_hi(unsigned v){ return __uint_as_float(v & 0xFFFF0000u); }

// ---------- CSR build ----------

__global__ void k_hist(const int* __restrict__ ei, int* __restrict__ cnt){
    int e = blockIdx.x*256 + threadIdx.x;
    if (e < NE) atomicAdd(&cnt[ei[NE + e]], 1);
}

__global__ void k_scan(int* __restrict__ cur){
    __shared__ int s[1024];
    int t = threadIdx.x;
    const int CH = 49;
    int base = t*CH;
    int m = NN - base; if (m > CH) m = CH; if (m < 0) m = 0;
    int sum = 0;
    for (int i = 0; i < m; ++i) sum += cur[base + i];
    s[t] = sum; __syncthreads();
    for (int off = 1; off < 1024; off <<= 1){
        int v = (t >= off) ? s[t - off] : 0; __syncthreads();
        s[t] += v; __syncthreads();
    }
    int run = s[t] - sum;
    for (int i = 0; i < m; ++i){
        int c = cur[base + i];
        cur[base + i] = run;
        run += c;
    }
}

// packed fill: ONE 4-byte store per edge (src in low 16, bf16 weight in high 16)
__global__ void k_fill(const int* __restrict__ ei, const float* __restrict__ ew,
                       int* __restrict__ cur, unsigned* __restrict__ csr){
    int e = blockIdx.x*256 + threadIdx.x;
    if (e >= NE) return;
    int src = ei[e], dst = ei[NE + e];
    int pos = atomicAdd(&cur[dst], 1);
    csr[pos] = (unsigned)src | (((unsigned)(ushort)rne_bf16(ew[e])) << 16);
}

// ---------- one-time prep ----------

__global__ void k_pad(const float* __restrict__ x, ushort* __restrict__ h2a){
    int idx = blockIdx.x*256 + threadIdx.x;
    int n = idx >> 7, f = idx & 127;
    float v = (f < FIN) ? x[n*FIN + f] : 0.f;
    h2a[idx] = (ushort)rne_bf16(v);
}

// fragWf[l] = bf16-frag( W_l @ w_ih^T )   [K=128][N=384]
__global__ void k_fuse(const float* __restrict__ W, const float* __restrict__ wih,
                       short* __restrict__ fwf){
    int idx = blockIdx.x*256 + threadIdx.x;   // 0..245759
    int l = idx / 49152;
    int r = idx % 49152;
    int k = r / 384, n = r % 384;
    const float* wl = W + l*16384 + k*128;
    const float* wi = wih + n*128;
    float acc = 0.f;
    for (int c = 0; c < 128; ++c) acc += wl[c]*wi[c];
    int lane = ((k>>3)&3)*16 + (n&15);
    fwf[l*49152 + (((n>>4)*4 + (k>>5))*64 + lane)*8 + (k&7)] = rne_bf16(acc);
}

__global__ void k_cvt_whh(const float* __restrict__ whh, short* __restrict__ fwhh){
    int idx = blockIdx.x*256 + threadIdx.x;   // 0..49151
    int k = idx / 384, n = idx % 384;
    float v = whh[n*128 + k];
    int lane = ((k>>3)&3)*16 + (n&15);
    fwhh[(((n>>4)*4 + (k>>5))*64 + lane)*8 + (k&7)] = rne_bf16(v);
}

__global__ void k_init_pool(unsigned* __restrict__ p){
    p[blockIdx.x*256 + threadIdx.x] = 0x007FFFFFu;   // enc(-inf)
}

// ---------- fused layer: aggregate -> dual MFMA GEMM -> register GRU ----------
// State is bf16-only (h2 ping-pong). Aggregation uses wave-uniform scalar CSR
// reads (readfirstlane bounds -> s_load stream), one vector gather per edge.
__global__ __launch_bounds__(256)
void k_layer(const ushort* __restrict__ h2r, ushort* __restrict__ h2w,
             const int* __restrict__ cur, const unsigned* __restrict__ csr,
             const short* __restrict__ fwf, const short* __restrict__ fwhh,
             const float* __restrict__ b_ih, const float* __restrict__ b_hh,
             const int* __restrict__ batch, unsigned* __restrict__ pooled,
             int last){
    __shared__ ushort tl[16*136];             // row stride 136 ushorts = 272B (16B-aligned)
    int tid = threadIdx.x;
    int n0 = blockIdx.x * 16;
    int wave = tid >> 6, lane = tid & 63;
    int lane_lo = lane & 15, quad = lane >> 4;

    // ---- phase 1: pull-aggregate 4 nodes per wave into LDS (bf16) ----
    unsigned* tld = (unsigned*)tl;
    const ushort* hp = h2r + lane*2;
    for (int sub = 0; sub < 4; ++sub){
        int node = n0 + wave*4 + sub;
        int start = __builtin_amdgcn_readfirstlane((node == 0) ? 0 : cur[node - 1]);
        int end   = __builtin_amdgcn_readfirstlane(cur[node]);
        float ax = 0.f, ay = 0.f;
        int i = start;
        for (; i + 8 <= end; i += 8){
            unsigned e0 = csr[i+0], e1 = csr[i+1], e2 = csr[i+2], e3 = csr[i+3];
            unsigned e4 = csr[i+4], e5 = csr[i+5], e6 = csr[i+6], e7 = csr[i+7];
            unsigned v0 = *(const unsigned*)(hp + (e0 & 0xFFFFu)*H);
            unsigned v1 = *(const unsigned*)(hp + (e1 & 0xFFFFu)*H);
            unsigned v2 = *(const unsigned*)(hp + (e2 & 0xFFFFu)*H);
            unsigned v3 = *(const unsigned*)(hp + (e3 & 0xFFFFu)*H);
            unsigned v4 = *(const unsigned*)(hp + (e4 & 0xFFFFu)*H);
            unsigned v5 = *(const unsigned*)(hp + (e5 & 0xFFFFu)*H);
            unsigned v6 = *(const unsigned*)(hp + (e6 & 0xFFFFu)*H);
            unsigned v7 = *(const unsigned*)(hp + (e7 & 0xFFFFu)*H);
            ax += bf_hi(e0)*bf_lo(v0); ay += bf_hi(e0)*bf_hi(v0);
            ax += bf_hi(e1)*bf_lo(v1); ay += bf_hi(e1)*bf_hi(v1);
            ax += bf_hi(e2)*bf_lo(v2); ay += bf_hi(e2)*bf_hi(v2);
            ax += bf_hi(e3)*bf_lo(v3); ay += bf_hi(e3)*bf_hi(v3);
            ax += bf_hi(e4)*bf_lo(v4); ay += bf_hi(e4)*bf_hi(v4);
            ax += bf_hi(e5)*bf_lo(v5); ay += bf_hi(e5)*bf_hi(v5);
            ax += bf_hi(e6)*bf_lo(v6); ay += bf_hi(e6)*bf_hi(v6);
            ax += bf_hi(e7)*bf_lo(v7); ay += bf_hi(e7)*bf_hi(v7);
        }
        for (; i < end; ++i){
            unsigned e = csr[i];
            unsigned v = *(const unsigned*)(hp + (e & 0xFFFFu)*H);
            ax += bf_hi(e)*bf_lo(v); ay += bf_hi(e)*bf_hi(v);
        }
        tld[(wave*4 + sub)*68 + lane] =
            ((unsigned)(ushort)rne_bf16(ax)) | (((unsigned)(ushort)rne_bf16(ay)) << 16);
    }
    __syncthreads();

    // ---- phase 2: dual GEMM; wave w owns cols w*32+{0..31} of each section ----
    f32x4 ai[6], ah[6];                       // [s*2 + t16]
    #pragma unroll
    for (int i = 0; i < 6; ++i){ ai[i] = (f32x4){0.f,0.f,0.f,0.f}; ah[i] = (f32x4){0.f,0.f,0.f,0.f}; }

    const ushort* arow_t = tl + lane_lo*136;
    const ushort* arow_h = h2r + (size_t)(n0 + lane_lo)*H;
    #pragma unroll
    for (int kt = 0; kt < 4; ++kt){
        short8 at  = *(const short8*)(arow_t + kt*32 + quad*8);
        short8 ahh = *(const short8*)(arow_h + kt*32 + quad*8);
        #pragma unroll
        for (int s = 0; s < 3; ++s){
            #pragma unroll
            for (int t16 = 0; t16 < 2; ++t16){
                int tile = (s*8 + wave*2 + t16)*4 + kt;
                short8 bi = *(const short8*)(fwf  + tile*512 + lane*8);
                short8 bh = *(const short8*)(fwhh + tile*512 + lane*8);
                ai[s*2+t16] = __builtin_amdgcn_mfma_f32_16x16x32_bf16(at,  bi, ai[s*2+t16], 0, 0, 0);
                ah[s*2+t16] = __builtin_amdgcn_mfma_f32_16x16x32_bf16(ahh, bh, ah[s*2+t16], 0, 0, 0);
            }
        }
    }

    // ---- phase 3: register-resident GRU update (+ fused pool on last) ----
    #pragma unroll
    for (int t16 = 0; t16 < 2; ++t16){
        int j = wave*32 + t16*16 + lane_lo;
        float bir = b_ih[j], biz = b_ih[128 + j], bin_ = b_ih[256 + j];
        float bhr = b_hh[j], bhz = b_hh[128 + j], bhn  = b_hh[256 + j];
        #pragma unroll
        for (int r = 0; r < 4; ++r){
            int row = n0 + quad*4 + r;
            float gir = ai[t16][r]     + bir, ghr = ah[t16][r]     + bhr;
            float giz = ai[2 + t16][r] + biz, ghz = ah[2 + t16][r] + bhz;
            float gin = ai[4 + t16][r] + bin_, ghn = ah[4 + t16][r] + bhn;
            float rr = 1.f/(1.f + __expf(-(gir + ghr)));
            float zz = 1.f/(1.f + __expf(-(giz + ghz)));
            float nn = tanhf(gin + rr*ghn);
            float ho = __uint_as_float(((unsigned)h2r[(size_t)row*H + j]) << 16);
            float hv = (1.f - zz)*nn + zz*ho;
            if (!last){
                h2w[(size_t)row*H + j] = (ushort)rne_bf16(hv);
            } else {
                int g = batch[row];
                unsigned u = __float_as_uint(hv);
                u = (u & 0x80000000u) ? ~u : (u | 0x80000000u);
                atomicMax(pooled + g*H + j, u);
            }
        }
    }
}

// ---------- tail ----------

__global__ void k_head(const unsigned* __restrict__ pooled,
                       const float* __restrict__ d1w, const float* __restrict__ d1b,
                       const float* __restrict__ d2w, const float* __restrict__ d2b,
                       float* __restrict__ out){
    __shared__ float sp[128];
    __shared__ float shid[512];
    int g = blockIdx.x, tid = threadIdx.x;
    if (tid < 128){
        unsigned u = pooled[g*H + tid];
        sp[tid] = __uint_as_float((u & 0x80000000u) ? (u ^ 0x80000000u) : ~u);
    }
    __syncthreads();
    for (int o = tid; o < 512; o += 256){
        float acc = d1b[o];
        for (int k = 0; k < H; ++k) acc += sp[k] * d1w[o*H + k];
        shid[o] = fmaxf(acc, 0.f);
    }
    __syncthreads();
    if (tid < NC){
        float acc = d2b[tid];
        for (int o = 0; o < 512; ++o) acc += shid[o] * d2w[tid*512 + o];
        out[g*NC + tid] = acc;
    }
}

extern "C" void kernel_launch(void* const* d_in, const int* in_sizes, int n_in,
                              void* d_out, int out_size, void* d_ws, size_t ws_size,
                              hipStream_t stream){
    const float* x     = (const float*)d_in[0];
    const int*   ei    = (const int*)d_in[1];
    const int*   batch = (const int*)d_in[2];
    const float* ew    = (const float*)d_in[3];
    const float* W     = (const float*)d_in[4];
    const float* wih   = (const float*)d_in[5];
    const float* whh   = (const float*)d_in[6];
    const float* bih   = (const float*)d_in[7];
    const float* bhh   = (const float*)d_in[8];
    const float* d1w   = (const float*)d_in[9];
    const float* d1b   = (const float*)d_in[10];
    const float* d2w   = (const float*)d_in[11];
    const float* d2b   = (const float*)d_in[12];
    float* out = (float*)d_out;

    float*  ws  = (float*)d_ws;
    ushort* h2a = (ushort*)(ws + OFF_H2A);
    ushort* h2b = (ushort*)(ws + OFF_H2B);
    int*    cur = (int*)(ws + OFF_CUR);
    unsigned* csr = (unsigned*)(ws + OFF_CSR);
    unsigned* pooled = (unsigned*)(ws + OFF_POOL);
    short*  fwf  = (short*)(ws + OFF_FWF);
    short*  fwhh = (short*)(ws + OFF_FWHH);

    hipMemsetAsync(cur, 0, (size_t)NN*sizeof(int), stream);
    k_hist<<<6250, 256, 0, stream>>>(ei, cur);
    k_scan<<<1, 1024, 0, stream>>>(cur);
    k_fill<<<6250, 256, 0, stream>>>(ei, ew, cur, csr);

    k_fuse<<<960, 256, 0, stream>>>(W, wih, fwf);
    k_cvt_whh<<<192, 256, 0, stream>>>(whh, fwhh);
    k_pad<<<25000, 256, 0, stream>>>(x, h2a);
    k_init_pool<<<256, 256, 0, stream>>>(pooled);

    for (int l = 0; l < NL; ++l){
        ushort* h2r = (l & 1) ? h2b : h2a;
        ushort* h2w = (l & 1) ? h2a : h2b;
        k_layer<<<3125, 256, 0, stream>>>(h2r, h2w, cur, csr,
                                          fwf + (size_t)l*49152, fwhh, bih, bhh,
                                          batch, pooled, (l == NL-1) ? 1 : 0);
    }

    k_head<<<NG, 256, 0, stream>>>(pooled, d1w, d1b, d2w, d2b, out);
}

// Round 14
// 927.781 us; speedup vs baseline: 1.0707x; 1.0060x over previous
//
#include <hip/hip_runtime.h>
#include <hip/hip_bf16.h>

#define NN 50000
#define NE 1600000
#define FIN 64
#define H 128
#define NL 5
#define NG 512
#define NC 10

typedef __attribute__((ext_vector_type(8))) short short8;
typedef __attribute__((ext_vector_type(4))) float f32x4;

// ws word offsets (~35 MB total)
#define OFF_H2A   0            // bf16 h ping (3.2M words)
#define OFF_H2B   3200000      // bf16 h pong (3.2M words)
#define OFF_CUR   6400000      // 50176 ints (hist counts -> fill cursor)
#define OFF_OFF   6450176      // 50176 ints (padded CSR starts, persistent)
#define OFF_CSR   6500352      // 2.0M packed words (ushort src | bf16 w << 16)
#define OFF_POOL  8500352      // 65536 unsigned
#define OFF_FWF   8565888      // 245760 shorts (5 x 128x384 bf16 frag)
#define OFF_FWHH  8688768      // 49152 shorts

__device__ __forceinline__ short rne_bf16(float f){
    unsigned u = __float_as_uint(f);
    unsigned r = (u + 0x7FFFu + ((u >> 16) & 1u)) >> 16;
    return (short)r;
}
__device__ __forceinline__ float bf_lo(unsigned v){ return __uint_as_float(v << 16); }
__device__ __forceinline__ float bf_hi(unsigned v){ return __uint_as_float(v & 0xFFFF0000u); }

// ---------- CSR build ----------

__global__ void k_hist(const int* __restrict__ ei, int* __restrict__ cnt){
    int e = blockIdx.x*256 + threadIdx.x;
    if (e < NE) atomicAdd(&cnt[ei[NE + e]], 1);
}

// exclusive scan of counts PADDED to multiples of 8; writes padded starts to
// both off[] (persistent) and cur[] (fill cursor). off[NN] = padded total.
__global__ void k_scan(int* __restrict__ cur, int* __restrict__ off){
    __shared__ int s[1024];
    int t = threadIdx.x;
    const int CH = 49;                       // 1024*49 >= 50001
    int base = t*CH;
    int m = (NN + 1) - base; if (m > CH) m = CH; if (m < 0) m = 0;
    int sum = 0;
    for (int i = 0; i < m; ++i) sum += (cur[base + i] + 7) & ~7;
    s[t] = sum; __syncthreads();
    for (int o = 1; o < 1024; o <<= 1){
        int v = (t >= o) ? s[t - o] : 0; __syncthreads();
        s[t] += v; __syncthreads();
    }
    int run = s[t] - sum;
    for (int i = 0; i < m; ++i){
        int c = (cur[base + i] + 7) & ~7;
        off[base + i] = run;
        cur[base + i] = run;
        run += c;
    }
}

// packed fill: ONE 4-byte store per edge; csr pre-zeroed so pad slots are
// (src=0, w=+0.0) dummy edges.
__global__ void k_fill(const int* __restrict__ ei, const float* __restrict__ ew,
                       int* __restrict__ cur, unsigned* __restrict__ csr){
    int e = blockIdx.x*256 + threadIdx.x;
    if (e >= NE) return;
    int src = ei[e], dst = ei[NE + e];
    int pos = atomicAdd(&cur[dst], 1);
    csr[pos] = (unsigned)src | (((unsigned)(ushort)rne_bf16(ew[e])) << 16);
}

// ---------- one-time prep ----------

__global__ void k_pad(const float* __restrict__ x, ushort* __restrict__ h2a){
    int idx = blockIdx.x*256 + threadIdx.x;
    int n = idx >> 7, f = idx & 127;
    float v = (f < FIN) ? x[n*FIN + f] : 0.f;
    h2a[idx] = (ushort)rne_bf16(v);
}

// fragWf[l] = bf16-frag( W_l @ w_ih^T )   [K=128][N=384]
__global__ void k_fuse(const float* __restrict__ W, const float* __restrict__ wih,
                       short* __restrict__ fwf){
    int idx = blockIdx.x*256 + threadIdx.x;   // 0..245759
    int l = idx / 49152;
    int r = idx % 49152;
    int k = r / 384, n = r % 384;
    const float* wl = W + l*16384 + k*128;
    const float* wi = wih + n*128;
    float acc = 0.f;
    for (int c = 0; c < 128; ++c) acc += wl[c]*wi[c];
    int lane = ((k>>3)&3)*16 + (n&15);
    fwf[l*49152 + (((n>>4)*4 + (k>>5))*64 + lane)*8 + (k&7)] = rne_bf16(acc);
}

__global__ void k_cvt_whh(const float* __restrict__ whh, short* __restrict__ fwhh){
    int idx = blockIdx.x*256 + threadIdx.x;   // 0..49151
    int k = idx / 384, n = idx % 384;
    float v = whh[n*128 + k];
    int lane = ((k>>3)&3)*16 + (n&15);
    fwhh[(((n>>4)*4 + (k>>5))*64 + lane)*8 + (k&7)] = rne_bf16(v);
}

__global__ void k_init_pool(unsigned* __restrict__ p){
    p[blockIdx.x*256 + threadIdx.x] = 0x007FFFFFu;   // enc(-inf)
}

// ---------- fused layer: aggregate -> dual MFMA GEMM -> register GRU ----------
// bf16-only state, ping-pong. Edge lists padded to x8 -> batch-only agg loop.
__global__ __launch_bounds__(256)
void k_layer(const ushort* __restrict__ h2r, ushort* __restrict__ h2w,
             const int* __restrict__ off, const unsigned* __restrict__ csr,
             const short* __restrict__ fwf, const short* __restrict__ fwhh,
             const float* __restrict__ b_ih, const float* __restrict__ b_hh,
             const int* __restrict__ batch, unsigned* __restrict__ pooled,
             int last){
    __shared__ ushort tl[16*136];             // row stride 136 ushorts (16B-aligned)
    int tid = threadIdx.x;
    int n0 = blockIdx.x * 16;
    int wave = tid >> 6, lane = tid & 63;
    int lane_lo = lane & 15, quad = lane >> 4;

    // ---- phase 1: pull-aggregate 4 nodes per wave into LDS (bf16) ----
    unsigned* tld = (unsigned*)tl;
    const ushort* hp = h2r + lane*2;
    for (int sub = 0; sub < 4; ++sub){
        int node = n0 + wave*4 + sub;
        int start = __builtin_amdgcn_readfirstlane(off[node]);
        int end   = __builtin_amdgcn_readfirstlane(off[node + 1]);
        float ax = 0.f, ay = 0.f;
        for (int i = start; i < end; i += 8){
            unsigned e0 = csr[i+0], e1 = csr[i+1], e2 = csr[i+2], e3 = csr[i+3];
            unsigned e4 = csr[i+4], e5 = csr[i+5], e6 = csr[i+6], e7 = csr[i+7];
            unsigned v0 = *(const unsigned*)(hp + (e0 & 0xFFFFu)*H);
            unsigned v1 = *(const unsigned*)(hp + (e1 & 0xFFFFu)*H);
            unsigned v2 = *(const unsigned*)(hp + (e2 & 0xFFFFu)*H);
            unsigned v3 = *(const unsigned*)(hp + (e3 & 0xFFFFu)*H);
            unsigned v4 = *(const unsigned*)(hp + (e4 & 0xFFFFu)*H);
            unsigned v5 = *(const unsigned*)(hp + (e5 & 0xFFFFu)*H);
            unsigned v6 = *(const unsigned*)(hp + (e6 & 0xFFFFu)*H);
            unsigned v7 = *(const unsigned*)(hp + (e7 & 0xFFFFu)*H);
            ax += bf_hi(e0)*bf_lo(v0); ay += bf_hi(e0)*bf_hi(v0);
            ax += bf_hi(e1)*bf_lo(v1); ay += bf_hi(e1)*bf_hi(v1);
            ax += bf_hi(e2)*bf_lo(v2); ay += bf_hi(e2)*bf_hi(v2);
            ax += bf_hi(e3)*bf_lo(v3); ay += bf_hi(e3)*bf_hi(v3);
            ax += bf_hi(e4)*bf_lo(v4); ay += bf_hi(e4)*bf_hi(v4);
            ax += bf_hi(e5)*bf_lo(v5); ay += bf_hi(e5)*bf_hi(v5);
            ax += bf_hi(e6)*bf_lo(v6); ay += bf_hi(e6)*bf_hi(v6);
            ax += bf_hi(e7)*bf_lo(v7); ay += bf_hi(e7)*bf_hi(v7);
        }
        tld[(wave*4 + sub)*68 + lane] =
            ((unsigned)(ushort)rne_bf16(ax)) | (((unsigned)(ushort)rne_bf16(ay)) << 16);
    }
    __syncthreads();

    // ---- phase 2: dual GEMM; wave w owns cols w*32+{0..31} of each section ----
    f32x4 ai[6], ah[6];                       // [s*2 + t16]
    #pragma unroll
    for (int i = 0; i < 6; ++i){ ai[i] = (f32x4){0.f,0.f,0.f,0.f}; ah[i] = (f32x4){0.f,0.f,0.f,0.f}; }

    const ushort* arow_t = tl + lane_lo*136;
    const ushort* arow_h = h2r + (size_t)(n0 + lane_lo)*H;
    #pragma unroll
    for (int kt = 0; kt < 4; ++kt){
        short8 at  = *(const short8*)(arow_t + kt*32 + quad*8);
        short8 ahh = *(const short8*)(arow_h + kt*32 + quad*8);
        #pragma unroll
        for (int s = 0; s < 3; ++s){
            #pragma unroll
            for (int t16 = 0; t16 < 2; ++t16){
                int tile = (s*8 + wave*2 + t16)*4 + kt;
                short8 bi = *(const short8*)(fwf  + tile*512 + lane*8);
                short8 bh = *(const short8*)(fwhh + tile*512 + lane*8);
                ai[s*2+t16] = __builtin_amdgcn_mfma_f32_16x16x32_bf16(at,  bi, ai[s*2+t16], 0, 0, 0);
                ah[s*2+t16] = __builtin_amdgcn_mfma_f32_16x16x32_bf16(ahh, bh, ah[s*2+t16], 0, 0, 0);
            }
        }
    }

    // ---- phase 3: register-resident GRU update (+ fused pool on last) ----
    #pragma unroll
    for (int t16 = 0; t16 < 2; ++t16){
        int j = wave*32 + t16*16 + lane_lo;
        float bir = b_ih[j], biz = b_ih[128 + j], bin_ = b_ih[256 + j];
        float bhr = b_hh[j], bhz = b_hh[128 + j], bhn  = b_hh[256 + j];
        #pragma unroll
        for (int r = 0; r < 4; ++r){
            int row = n0 + quad*4 + r;
            float gir = ai[t16][r]     + bir, ghr = ah[t16][r]     + bhr;
            float giz = ai[2 + t16][r] + biz, ghz = ah[2 + t16][r] + bhz;
            float gin = ai[4 + t16][r] + bin_, ghn = ah[4 + t16][r] + bhn;
            float rr = 1.f/(1.f + __expf(-(gir + ghr)));
            float zz = 1.f/(1.f + __expf(-(giz + ghz)));
            float nn = tanhf(gin + rr*ghn);
            float ho = __uint_as_float(((unsigned)h2r[(size_t)row*H + j]) << 16);
            float hv = (1.f - zz)*nn + zz*ho;
            if (!last){
                h2w[(size_t)row*H + j] = (ushort)rne_bf16(hv);
            } else {
                int g = batch[row];
                unsigned u = __float_as_uint(hv);
                u = (u & 0x80000000u) ? ~u : (u | 0x80000000u);
                atomicMax(pooled + g*H + j, u);
            }
        }
    }
}

// ---------- tail ----------

__global__ void k_head(const unsigned* __restrict__ pooled,
                       const float* __restrict__ d1w, const float* __restrict__ d1b,
                       const float* __restrict__ d2w, const float* __restrict__ d2b,
                       float* __restrict__ out){
    __shared__ float sp[128];
    __shared__ float shid[512];
    int g = blockIdx.x, tid = threadIdx.x;
    if (tid < 128){
        unsigned u = pooled[g*H + tid];
        sp[tid] = __uint_as_float((u & 0x80000000u) ? (u ^ 0x80000000u) : ~u);
    }
    __syncthreads();
    for (int o = tid; o < 512; o += 256){
        float acc = d1b[o];
        for (int k = 0; k < H; ++k) acc += sp[k] * d1w[o*H + k];
        shid[o] = fmaxf(acc, 0.f);
    }
    __syncthreads();
    if (tid < NC){
        float acc = d2b[tid];
        for (int o = 0; o < 512; ++o) acc += shid[o] * d2w[tid*512 + o];
        out[g*NC + tid] = acc;
    }
}

extern "C" void kernel_launch(void* const* d_in, const int* in_sizes, int n_in,
                              void* d_out, int out_size, void* d_ws, size_t ws_size,
                              hipStream_t stream){
    const float* x     = (const float*)d_in[0];
    const int*   ei    = (const int*)d_in[1];
    const int*   batch = (const int*)d_in[2];
    const float* ew    = (const float*)d_in[3];
    const float* W     = (const float*)d_in[4];
    const float* wih   = (const float*)d_in[5];
    const float* whh   = (const float*)d_in[6];
    const float* bih   = (const float*)d_in[7];
    const float* bhh   = (const float*)d_in[8];
    const float* d1w   = (const float*)d_in[9];
    const float* d1b   = (const float*)d_in[10];
    const float* d2w   = (const float*)d_in[11];
    const float* d2b   = (const float*)d_in[12];
    float* out = (float*)d_out;

    float*  ws  = (float*)d_ws;
    ushort* h2a = (ushort*)(ws + OFF_H2A);
    ushort* h2b = (ushort*)(ws + OFF_H2B);
    int*    cur = (int*)(ws + OFF_CUR);
    int*    off = (int*)(ws + OFF_OFF);
    unsigned* csr = (unsigned*)(ws + OFF_CSR);
    unsigned* pooled = (unsigned*)(ws + OFF_POOL);
    short*  fwf  = (short*)(ws + OFF_FWF);
    short*  fwhh = (short*)(ws + OFF_FWHH);

    hipMemsetAsync(cur, 0, 50176*sizeof(int), stream);
    hipMemsetAsync(csr, 0, 2000000*sizeof(unsigned), stream);   // pad slots = dummy edges
    k_hist<<<6250, 256, 0, stream>>>(ei, cur);
    k_scan<<<1, 1024, 0, stream>>>(cur, off);
    k_fill<<<6250, 256, 0, stream>>>(ei, ew, cur, csr);

    k_fuse<<<960, 256, 0, stream>>>(W, wih, fwf);
    k_cvt_whh<<<192, 256, 0, stream>>>(whh, fwhh);
    k_pad<<<25000, 256, 0, stream>>>(x, h2a);
    k_init_pool<<<256, 256, 0, stream>>>(pooled);

    for (int l = 0; l < NL; ++l){
        ushort* h2r = (l & 1) ? h2b : h2a;
        ushort* h2w = (l & 1) ? h2a : h2b;
        k_layer<<<3125, 256, 0, stream>>>(h2r, h2w, off, csr,
                                          fwf + (size_t)l*49152, fwhh, bih, bhh,
                                          batch, pooled, (l == NL-1) ? 1 : 0);
    }

    k_head<<<NG, 256, 0, stream>>>(pooled, d1w, d1b, d2w, d2b, out);
}

// Round 15
// 920.502 us; speedup vs baseline: 1.0791x; 1.0079x over previous
//
#include <hip/hip_runtime.h>
#include <hip/hip_bf16.h>

#define NN 50000
#define NE 1600000
#define FIN 64
#define H 128
#define NL 5
#define NG 512
#define NC 10

typedef __attribute__((ext_vector_type(8))) short short8;
typedef __attribute__((ext_vector_type(4))) float f32x4;

// ws word offsets (~37 MB total)
#define OFF_H2A   0            // bf16 h ping (3.2M words)
#define OFF_H2B   3200000      // bf16 h pong (3.2M words)
#define OFF_CUR   6400000      // 50176 ints (hist counts -> fill cursor)
#define OFF_OFF   6450176      // 50176 ints (padded CSR starts, persistent)
#define OFF_CSR   6500352      // 2.4M packed words (ushort src | bf16 w << 16)
#define OFF_POOL  8900352      // 65536 unsigned
#define OFF_FWF   8965888      // 245760 shorts (5 x 128x384 bf16 frag)
#define OFF_FWHH  9088768      // 49152 shorts

__device__ __forceinline__ short rne_bf16(float f){
    unsigned u = __float_as_uint(f);
    unsigned r = (u + 0x7FFFu + ((u >> 16) & 1u)) >> 16;
    return (short)r;
}
__device__ __forceinline__ float bf_lo(unsigned v){ return __uint_as_float(v << 16); }
__device__ __forceinline__ float bf_hi(unsigned v){ return __uint_as_float(v & 0xFFFF0000u); }

// ---------- CSR build ----------

__global__ void k_hist(const int* __restrict__ ei, int* __restrict__ cnt){
    int e = blockIdx.x*256 + threadIdx.x;
    if (e < NE) atomicAdd(&cnt[ei[NE + e]], 1);
}

// exclusive scan of counts PADDED to multiples of 16; starts to off[] + cur[].
__global__ void k_scan(int* __restrict__ cur, int* __restrict__ off){
    __shared__ int s[1024];
    int t = threadIdx.x;
    const int CH = 49;                       // 1024*49 >= 50001
    int base = t*CH;
    int m = (NN + 1) - base; if (m > CH) m = CH; if (m < 0) m = 0;
    int sum = 0;
    for (int i = 0; i < m; ++i) sum += (cur[base + i] + 15) & ~15;
    s[t] = sum; __syncthreads();
    for (int o = 1; o < 1024; o <<= 1){
        int v = (t >= o) ? s[t - o] : 0; __syncthreads();
        s[t] += v; __syncthreads();
    }
    int run = s[t] - sum;
    for (int i = 0; i < m; ++i){
        int c = (cur[base + i] + 15) & ~15;
        off[base + i] = run;
        cur[base + i] = run;
        run += c;
    }
}

// packed fill: ONE 4-byte store per edge; csr pre-zeroed so pad slots are
// (src=0, w=+0.0) dummy edges.
__global__ void k_fill(const int* __restrict__ ei, const float* __restrict__ ew,
                       int* __restrict__ cur, unsigned* __restrict__ csr){
    int e = blockIdx.x*256 + threadIdx.x;
    if (e >= NE) return;
    int src = ei[e], dst = ei[NE + e];
    int pos = atomicAdd(&cur[dst], 1);
    csr[pos] = (unsigned)src | (((unsigned)(ushort)rne_bf16(ew[e])) << 16);
}

// ---------- one-time prep ----------

__global__ void k_pad(const float* __restrict__ x, ushort* __restrict__ h2a){
    int idx = blockIdx.x*256 + threadIdx.x;
    int n = idx >> 7, f = idx & 127;
    float v = (f < FIN) ? x[n*FIN + f] : 0.f;
    h2a[idx] = (ushort)rne_bf16(v);
}

// fragWf[l] = bf16-frag( W_l @ w_ih^T )   [K=128][N=384]
__global__ void k_fuse(const float* __restrict__ W, const float* __restrict__ wih,
                       short* __restrict__ fwf){
    int idx = blockIdx.x*256 + threadIdx.x;   // 0..245759
    int l = idx / 49152;
    int r = idx % 49152;
    int k = r / 384, n = r % 384;
    const float* wl = W + l*16384 + k*128;
    const float* wi = wih + n*128;
    float acc = 0.f;
    for (int c = 0; c < 128; ++c) acc += wl[c]*wi[c];
    int lane = ((k>>3)&3)*16 + (n&15);
    fwf[l*49152 + (((n>>4)*4 + (k>>5))*64 + lane)*8 + (k&7)] = rne_bf16(acc);
}

__global__ void k_cvt_whh(const float* __restrict__ whh, short* __restrict__ fwhh){
    int idx = blockIdx.x*256 + threadIdx.x;   // 0..49151
    int k = idx / 384, n = idx % 384;
    float v = whh[n*128 + k];
    int lane = ((k>>3)&3)*16 + (n&15);
    fwhh[(((n>>4)*4 + (k>>5))*64 + lane)*8 + (k&7)] = rne_bf16(v);
}

__global__ void k_init_pool(unsigned* __restrict__ p){
    p[blockIdx.x*256 + threadIdx.x] = 0x007FFFFFu;   // enc(-inf)
}

// ---------- fused layer: aggregate -> dual MFMA GEMM -> register GRU ----------
// Phase 1: 4 edges per gather instruction. grp=lane>>4 picks edge, fl=lane&15
// covers 16B (8 features). One csr dwordx4 + 4 gather dwordx4 per 16 edges.
__global__ __launch_bounds__(256)
void k_layer(const ushort* __restrict__ h2r, ushort* __restrict__ h2w,
             const int* __restrict__ off, const unsigned* __restrict__ csr,
             const short* __restrict__ fwf, const short* __restrict__ fwhh,
             const float* __restrict__ b_ih, const float* __restrict__ b_hh,
             const int* __restrict__ batch, unsigned* __restrict__ pooled,
             int last){
    __shared__ ushort tl[16*136];             // row stride 136 ushorts (16B-aligned)
    int tid = threadIdx.x;
    int n0 = blockIdx.x * 16;
    int wave = tid >> 6, lane = tid & 63;
    int lane_lo = lane & 15, quad = lane >> 4;
    int grp = lane >> 4, fl = lane & 15;

    // ---- phase 1: pull-aggregate 4 nodes per wave into LDS (bf16) ----
    for (int sub = 0; sub < 4; ++sub){
        int node = n0 + wave*4 + sub;
        int start = __builtin_amdgcn_readfirstlane(off[node]);
        int end   = __builtin_amdgcn_readfirstlane(off[node + 1]);
        float a0=0.f,a1=0.f,a2=0.f,a3=0.f,a4=0.f,a5=0.f,a6=0.f,a7=0.f;
        const ushort* hb = h2r + fl*8;
        for (int i = start; i < end; i += 16){
            uint4 c = *(const uint4*)(csr + i + grp*4);
            uint4 v0 = *(const uint4*)(hb + (c.x & 0xFFFFu)*H);
            uint4 v1 = *(const uint4*)(hb + (c.y & 0xFFFFu)*H);
            uint4 v2 = *(const uint4*)(hb + (c.z & 0xFFFFu)*H);
            uint4 v3 = *(const uint4*)(hb + (c.w & 0xFFFFu)*H);
            float w0 = bf_hi(c.x), w1 = bf_hi(c.y), w2 = bf_hi(c.z), w3 = bf_hi(c.w);
            a0 += w0*bf_lo(v0.x); a1 += w0*bf_hi(v0.x); a2 += w0*bf_lo(v0.y); a3 += w0*bf_hi(v0.y);
            a4 += w0*bf_lo(v0.z); a5 += w0*bf_hi(v0.z); a6 += w0*bf_lo(v0.w); a7 += w0*bf_hi(v0.w);
            a0 += w1*bf_lo(v1.x); a1 += w1*bf_hi(v1.x); a2 += w1*bf_lo(v1.y); a3 += w1*bf_hi(v1.y);
            a4 += w1*bf_lo(v1.z); a5 += w1*bf_hi(v1.z); a6 += w1*bf_lo(v1.w); a7 += w1*bf_hi(v1.w);
            a0 += w2*bf_lo(v2.x); a1 += w2*bf_hi(v2.x); a2 += w2*bf_lo(v2.y); a3 += w2*bf_hi(v2.y);
            a4 += w2*bf_lo(v2.z); a5 += w2*bf_hi(v2.z); a6 += w2*bf_lo(v2.w); a7 += w2*bf_hi(v2.w);
            a0 += w3*bf_lo(v3.x); a1 += w3*bf_hi(v3.x); a2 += w3*bf_lo(v3.y); a3 += w3*bf_hi(v3.y);
            a4 += w3*bf_lo(v3.z); a5 += w3*bf_hi(v3.z); a6 += w3*bf_lo(v3.w); a7 += w3*bf_hi(v3.w);
        }
        // reduce across the 4 groups (each held a disjoint edge subset)
        a0 += __shfl_xor(a0,16); a1 += __shfl_xor(a1,16); a2 += __shfl_xor(a2,16); a3 += __shfl_xor(a3,16);
        a4 += __shfl_xor(a4,16); a5 += __shfl_xor(a5,16); a6 += __shfl_xor(a6,16); a7 += __shfl_xor(a7,16);
        a0 += __shfl_xor(a0,32); a1 += __shfl_xor(a1,32); a2 += __shfl_xor(a2,32); a3 += __shfl_xor(a3,32);
        a4 += __shfl_xor(a4,32); a5 += __shfl_xor(a5,32); a6 += __shfl_xor(a6,32); a7 += __shfl_xor(a7,32);
        if (lane < 16){
            short8 hbv;
            hbv[0]=rne_bf16(a0); hbv[1]=rne_bf16(a1); hbv[2]=rne_bf16(a2); hbv[3]=rne_bf16(a3);
            hbv[4]=rne_bf16(a4); hbv[5]=rne_bf16(a5); hbv[6]=rne_bf16(a6); hbv[7]=rne_bf16(a7);
            *(short8*)(tl + (wave*4 + sub)*136 + fl*8) = hbv;
        }
    }
    __syncthreads();

    // ---- phase 2: dual GEMM; wave w owns cols w*32+{0..31} of each section ----
    f32x4 ai[6], ah[6];                       // [s*2 + t16]
    #pragma unroll
    for (int i = 0; i < 6; ++i){ ai[i] = (f32x4){0.f,0.f,0.f,0.f}; ah[i] = (f32x4){0.f,0.f,0.f,0.f}; }

    const ushort* arow_t = tl + lane_lo*136;
    const ushort* arow_h = h2r + (size_t)(n0 + lane_lo)*H;
    #pragma unroll
    for (int kt = 0; kt < 4; ++kt){
        short8 at  = *(const short8*)(arow_t + kt*32 + quad*8);
        short8 ahh = *(const short8*)(arow_h + kt*32 + quad*8);
        #pragma unroll
        for (int s = 0; s < 3; ++s){
            #pragma unroll
            for (int t16 = 0; t16 < 2; ++t16){
                int tile = (s*8 + wave*2 + t16)*4 + kt;
                short8 bi = *(const short8*)(fwf  + tile*512 + lane*8);
                short8 bh = *(const short8*)(fwhh + tile*512 + lane*8);
                ai[s*2+t16] = __builtin_amdgcn_mfma_f32_16x16x32_bf16(at,  bi, ai[s*2+t16], 0, 0, 0);
                ah[s*2+t16] = __builtin_amdgcn_mfma_f32_16x16x32_bf16(ahh, bh, ah[s*2+t16], 0, 0, 0);
            }
        }
    }

    // ---- phase 3: register-resident GRU update (+ fused pool on last) ----
    #pragma unroll
    for (int t16 = 0; t16 < 2; ++t16){
        int j = wave*32 + t16*16 + lane_lo;
        float bir = b_ih[j], biz = b_ih[128 + j], bin_ = b_ih[256 + j];
        float bhr = b_hh[j], bhz = b_hh[128 + j], bhn  = b_hh[256 + j];
        #pragma unroll
        for (int r = 0; r < 4; ++r){
            int row = n0 + quad*4 + r;
            float gir = ai[t16][r]     + bir, ghr = ah[t16][r]     + bhr;
            float giz = ai[2 + t16][r] + biz, ghz = ah[2 + t16][r] + bhz;
            float gin = ai[4 + t16][r] + bin_, ghn = ah[4 + t16][r] + bhn;
            float rr = 1.f/(1.f + __expf(-(gir + ghr)));
            float zz = 1.f/(1.f + __expf(-(giz + ghz)));
            float nn = tanhf(gin + rr*ghn);
            float ho = __uint_as_float(((unsigned)h2r[(size_t)row*H + j]) << 16);
            float hv = (1.f - zz)*nn + zz*ho;
            if (!last){
                h2w[(size_t)row*H + j] = (ushort)rne_bf16(hv);
            } else {
                int g = batch[row];
                unsigned u = __float_as_uint(hv);
                u = (u & 0x80000000u) ? ~u : (u | 0x80000000u);
                atomicMax(pooled + g*H + j, u);
            }
        }
    }
}

// ---------- tail ----------

__global__ void k_head(const unsigned* __restrict__ pooled,
                       const float* __restrict__ d1w, const float* __restrict__ d1b,
                       const float* __restrict__ d2w, const float* __restrict__ d2b,
                       float* __restrict__ out){
    __shared__ float sp[128];
    __shared__ float shid[512];
    int g = blockIdx.x, tid = threadIdx.x;
    if (tid < 128){
        unsigned u = pooled[g*H + tid];
        sp[tid] = __uint_as_float((u & 0x80000000u) ? (u ^ 0x80000000u) : ~u);
    }
    __syncthreads();
    for (int o = tid; o < 512; o += 256){
        float acc = d1b[o];
        for (int k = 0; k < H; ++k) acc += sp[k] * d1w[o*H + k];
        shid[o] = fmaxf(acc, 0.f);
    }
    __syncthreads();
    if (tid < NC){
        float acc = d2b[tid];
        for (int o = 0; o < 512; ++o) acc += shid[o] * d2w[tid*512 + o];
        out[g*NC + tid] = acc;
    }
}

extern "C" void kernel_launch(void* const* d_in, const int* in_sizes, int n_in,
                              void* d_out, int out_size, void* d_ws, size_t ws_size,
                              hipStream_t stream){
    const float* x     = (const float*)d_in[0];
    const int*   ei    = (const int*)d_in[1];
    const int*   batch = (const int*)d_in[2];
    const float* ew    = (const float*)d_in[3];
    const float* W     = (const float*)d_in[4];
    const float* wih   = (const float*)d_in[5];
    const float* whh   = (const float*)d_in[6];
    const float* bih   = (const float*)d_in[7];
    const float* bhh   = (const float*)d_in[8];
    const float* d1w   = (const float*)d_in[9];
    const float* d1b   = (const float*)d_in[10];
    const float* d2w   = (const float*)d_in[11];
    const float* d2b   = (const float*)d_in[12];
    float* out = (float*)d_out;

    float*  ws  = (float*)d_ws;
    ushort* h2a = (ushort*)(ws + OFF_H2A);
    ushort* h2b = (ushort*)(ws + OFF_H2B);
    int*    cur = (int*)(ws + OFF_CUR);
    int*    off = (int*)(ws + OFF_OFF);
    unsigned* csr = (unsigned*)(ws + OFF_CSR);
    unsigned* pooled = (unsigned*)(ws + OFF_POOL);
    short*  fwf  = (short*)(ws + OFF_FWF);
    short*  fwhh = (short*)(ws + OFF_FWHH);

    hipMemsetAsync(cur, 0, 50176*sizeof(int), stream);
    hipMemsetAsync(csr, 0, 2400000*sizeof(unsigned), stream);   // pad slots = dummy edges
    k_hist<<<6250, 256, 0, stream>>>(ei, cur);
    k_scan<<<1, 1024, 0, stream>>>(cur, off);
    k_fill<<<6250, 256, 0, stream>>>(ei, ew, cur, csr);

    k_fuse<<<960, 256, 0, stream>>>(W, wih, fwf);
    k_cvt_whh<<<192, 256, 0, stream>>>(whh, fwhh);
    k_pad<<<25000, 256, 0, stream>>>(x, h2a);
    k_init_pool<<<256, 256, 0, stream>>>(pooled);

    for (int l = 0; l < NL; ++l){
        ushort* h2r = (l & 1) ? h2b : h2a;
        ushort* h2w = (l & 1) ? h2a : h2b;
        k_layer<<<3125, 256, 0, stream>>>(h2r, h2w, off, csr,
                                          fwf + (size_t)l*49152, fwhh, bih, bhh,
                                          batch, pooled, (l == NL-1) ? 1 : 0);
    }

    k_head<<<NG, 256, 0, stream>>>(pooled, d1w, d1b, d2w, d2b, out);
}